// Round 1
// baseline (175.917 us; speedup 1.0000x reference)
//
#include <hip/hip_runtime.h>

#define TOK_S   4096      // sequence length (= row length of src)
#define RPB     8         // rows per block
#define NBI     1089      // 33*33 bigram bins
#define NBI_PAD 1092      // padded to multiple of 4 (row stride 4368 B, 16B-aligned)
#define NTRI    512       // trigram buckets

__global__ __launch_bounds__(256, 2)
void ngram_fused(const int* __restrict__ src,
                 const float* __restrict__ Wb1, const float* __restrict__ bb1,
                 const float* __restrict__ Wb2, const float* __restrict__ bb2,
                 const float* __restrict__ Wt1, const float* __restrict__ bt1,
                 const float* __restrict__ Wt2, const float* __restrict__ bt2,
                 float* __restrict__ out)
{
    __shared__ int   s_row[TOK_S];           // 16 KB (one row staged at a time)
    __shared__ int   s_bi [RPB][NBI_PAD];    // 34.9 KB
    __shared__ int   s_tri[RPB][NTRI];       // 16 KB
    __shared__ int   s_len[RPB][2];
    __shared__ float s_h  [RPB][256];        // 8 KB (bi hidden, reused for tri)

    const int tid  = threadIdx.x;
    const int row0 = blockIdx.x * RPB;

    // ---- zero histograms ----
    for (int i = tid; i < RPB * NBI_PAD; i += 256) ((int*)s_bi)[i] = 0;
    for (int i = tid; i < RPB * NTRI;    i += 256) ((int*)s_tri)[i] = 0;
    if (tid < RPB * 2) ((int*)s_len)[tid] = 0;
    __syncthreads();

    // ---- histogram phase: one row at a time, staged in LDS ----
    for (int r = 0; r < RPB; ++r) {
        const int4* p = (const int4*)(src + (size_t)(row0 + r) * TOK_S);
        for (int i = tid; i < TOK_S / 4; i += 256) ((int4*)s_row)[i] = p[i];
        __syncthreads();

        int bcnt = 0, tcnt = 0;
        for (int i = tid; i < TOK_S - 1; i += 256) {
            int c1 = s_row[i], c2 = s_row[i + 1];
            bool m12 = (c1 > 0) & (c2 > 0);
            if (m12) { atomicAdd(&s_bi[r][c1 * 33 + c2], 1); bcnt++; }
            if (i < TOK_S - 2) {
                int c3 = s_row[i + 2];
                if (m12 & (c3 > 0)) {
                    atomicAdd(&s_tri[r][(c1 * 1089 + c2 * 33 + c3) & 511], 1);
                    tcnt++;
                }
            }
        }
        atomicAdd(&s_len[r][0], bcnt);
        atomicAdd(&s_len[r][1], tcnt);
        __syncthreads();   // also protects s_row before next row overwrites it
    }

    // ---- reciprocal lengths; convert counts int -> float in place ----
    float invb[RPB], invt[RPB];
    #pragma unroll
    for (int r = 0; r < RPB; ++r) {
        invb[r] = 1.0f / fmaxf((float)s_len[r][0], 1.0f);
        invt[r] = 1.0f / fmaxf((float)s_len[r][1], 1.0f);
    }
    for (int i = tid; i < RPB * NBI_PAD; i += 256) {
        int v = ((int*)s_bi)[i];  ((float*)s_bi)[i]  = (float)v;
    }
    for (int i = tid; i < RPB * NTRI; i += 256) {
        int v = ((int*)s_tri)[i]; ((float*)s_tri)[i] = (float)v;
    }
    __syncthreads();

    const float* fbi = (const float*)s_bi;
    const float* ftr = (const float*)s_tri;

    // ---- bigram layer 1: hidden[j] = relu((counts . Wb1[:,j]) * inv + bb1[j]) ----
    {
        const int j = tid;
        float acc[RPB] = {0.f,0.f,0.f,0.f,0.f,0.f,0.f,0.f};
        int bin = 0;
        for (; bin + 4 <= NBI; bin += 4) {
            float w0 = Wb1[(bin + 0) * 256 + j];
            float w1 = Wb1[(bin + 1) * 256 + j];
            float w2 = Wb1[(bin + 2) * 256 + j];
            float w3 = Wb1[(bin + 3) * 256 + j];
            #pragma unroll
            for (int r = 0; r < RPB; ++r) {
                const float4 c = *(const float4*)&fbi[r * NBI_PAD + bin];
                acc[r] = fmaf(c.x, w0, acc[r]);
                acc[r] = fmaf(c.y, w1, acc[r]);
                acc[r] = fmaf(c.z, w2, acc[r]);
                acc[r] = fmaf(c.w, w3, acc[r]);
            }
        }
        for (; bin < NBI; ++bin) {          // remainder (bin 1088)
            float w = Wb1[bin * 256 + j];
            #pragma unroll
            for (int r = 0; r < RPB; ++r)
                acc[r] = fmaf(fbi[r * NBI_PAD + bin], w, acc[r]);
        }
        float b = bb1[j];
        #pragma unroll
        for (int r = 0; r < RPB; ++r)
            s_h[r][j] = fmaxf(fmaf(acc[r], invb[r], b), 0.0f);
    }
    __syncthreads();

    // ---- bigram layer 2: out[:, 0:32] ----
    {
        const int r = tid >> 5, o = tid & 31;
        float acc = bb2[o];
        #pragma unroll 4
        for (int j = 0; j < 256; ++j)
            acc = fmaf(s_h[r][j], Wb2[j * 32 + o], acc);
        out[(size_t)(row0 + r) * 64 + o] = acc;
    }
    __syncthreads();

    // ---- trigram layer 1 ----
    {
        const int j = tid;
        float acc[RPB] = {0.f,0.f,0.f,0.f,0.f,0.f,0.f,0.f};
        for (int bin = 0; bin < NTRI; bin += 4) {
            float w0 = Wt1[(bin + 0) * 256 + j];
            float w1 = Wt1[(bin + 1) * 256 + j];
            float w2 = Wt1[(bin + 2) * 256 + j];
            float w3 = Wt1[(bin + 3) * 256 + j];
            #pragma unroll
            for (int r = 0; r < RPB; ++r) {
                const float4 c = *(const float4*)&ftr[r * NTRI + bin];
                acc[r] = fmaf(c.x, w0, acc[r]);
                acc[r] = fmaf(c.y, w1, acc[r]);
                acc[r] = fmaf(c.z, w2, acc[r]);
                acc[r] = fmaf(c.w, w3, acc[r]);
            }
        }
        float b = bt1[j];
        #pragma unroll
        for (int r = 0; r < RPB; ++r)
            s_h[r][j] = fmaxf(fmaf(acc[r], invt[r], b), 0.0f);
    }
    __syncthreads();

    // ---- trigram layer 2: out[:, 32:64] ----
    {
        const int r = tid >> 5, o = tid & 31;
        float acc = bt2[o];
        #pragma unroll 4
        for (int j = 0; j < 256; ++j)
            acc = fmaf(s_h[r][j], Wt2[j * 32 + o], acc);
        out[(size_t)(row0 + r) * 64 + 32 + o] = acc;
    }
}

extern "C" void kernel_launch(void* const* d_in, const int* in_sizes, int n_in,
                              void* d_out, int out_size, void* d_ws, size_t ws_size,
                              hipStream_t stream) {
    const int*   src = (const int*)  d_in[0];
    const float* Wb1 = (const float*)d_in[1];
    const float* bb1 = (const float*)d_in[2];
    const float* Wb2 = (const float*)d_in[3];
    const float* bb2 = (const float*)d_in[4];
    const float* Wt1 = (const float*)d_in[5];
    const float* bt1 = (const float*)d_in[6];
    const float* Wt2 = (const float*)d_in[7];
    const float* bt2 = (const float*)d_in[8];
    float* outp = (float*)d_out;

    const int B = in_sizes[0] / TOK_S;   // 4096
    dim3 grid(B / RPB);                  // 512 blocks
    ngram_fused<<<grid, 256, 0, stream>>>(src, Wb1, bb1, Wb2, bb2,
                                          Wt1, bt1, Wt2, bt2, outp);
}

// Round 2
// 94.787 us; speedup vs baseline: 1.8559x; 1.8559x over previous
//
#include <hip/hip_runtime.h>
#include <hip/hip_bf16.h>

#define TOK_S    4096
#define NBI      1089      // 33*33
#define KP_BI    1120      // padded to multiple of 32
#define NTRI     512       // already multiple of 32
#define NHID     256

typedef __attribute__((ext_vector_type(8))) short short8;   // 8 bf16 (4 VGPRs)
typedef __attribute__((ext_vector_type(4))) float f32x4;

// ---------------- K0: transpose + bf16-convert W1 ----------------
// W [K][256] fp32  ->  WT [256][Kp] bf16, pad (k>=K) zeroed.
__global__ __launch_bounds__(256)
void transpose_w(const float* __restrict__ W, __hip_bfloat16* __restrict__ WT,
                 int K, int Kp)
{
    int idx = blockIdx.x * 256 + threadIdx.x;
    if (idx >= NHID * Kp) return;
    int c = idx / Kp, k = idx - c * Kp;
    float v = (k < K) ? W[k * NHID + c] : 0.0f;
    WT[idx] = __float2bfloat16(v);
}

// ---------------- K1: per-row histograms -> raw bf16 counts ----------------
__global__ __launch_bounds__(256)
void hist_kernel(const int* __restrict__ src,
                 __hip_bfloat16* __restrict__ Abi,
                 __hip_bfloat16* __restrict__ Atri,
                 float* __restrict__ inv)
{
    __shared__ int s_row[TOK_S];     // 16 KB
    __shared__ int s_bi[NBI];
    __shared__ int s_tri[NTRI];
    __shared__ int s_len[2];

    const int tid = threadIdx.x;
    const size_t row = blockIdx.x;

    for (int i = tid; i < NBI;  i += 256) s_bi[i] = 0;
    for (int i = tid; i < NTRI; i += 256) s_tri[i] = 0;
    if (tid < 2) s_len[tid] = 0;

    const int4* p = (const int4*)(src + row * TOK_S);
    for (int i = tid; i < TOK_S / 4; i += 256) ((int4*)s_row)[i] = p[i];
    __syncthreads();

    int bc = 0, tc = 0;
    for (int i = tid; i < TOK_S - 1; i += 256) {
        int c1 = s_row[i], c2 = s_row[i + 1];
        bool m = (c1 > 0) & (c2 > 0);
        if (m) { atomicAdd(&s_bi[c1 * 33 + c2], 1); bc++; }
        if (i < TOK_S - 2) {
            int c3 = s_row[i + 2];
            if (m & (c3 > 0)) {
                atomicAdd(&s_tri[(c1 * 1089 + c2 * 33 + c3) & (NTRI - 1)], 1);
                tc++;
            }
        }
    }
    atomicAdd(&s_len[0], bc);
    atomicAdd(&s_len[1], tc);
    __syncthreads();

    // raw counts (exact in bf16: small ints); normalization applied post-GEMM
    __hip_bfloat16* arow = Abi + row * KP_BI;
    for (int i = tid; i < KP_BI; i += 256) {
        float v = (i < NBI) ? (float)s_bi[i] : 0.0f;
        arow[i] = __float2bfloat16(v);
    }
    __hip_bfloat16* trow = Atri + row * NTRI;
    for (int i = tid; i < NTRI; i += 256)
        trow[i] = __float2bfloat16((float)s_tri[i]);

    if (tid == 0) {
        inv[row * 2 + 0] = 1.0f / fmaxf((float)s_len[0], 1.0f);
        inv[row * 2 + 1] = 1.0f / fmaxf((float)s_len[1], 1.0f);
    }
}

// ---------------- K2: bf16 MFMA GEMM + relu + /len -> H fp32 ----------------
// C[M x 256] = A[M x Kp](counts) @ WT^T ; H = relu(C * inv + b1)
// BM=64, BN=64, 4 waves as 2x2, wave tile 32x32 (2x2 fragments of 16x16x32).
// No LDS: fragments loaded directly from global (L2-resident).
__global__ __launch_bounds__(256)
void gemm_mlp1(const __hip_bfloat16* __restrict__ Abi,
               const __hip_bfloat16* __restrict__ WbT,
               const float* __restrict__ bb1,
               const __hip_bfloat16* __restrict__ Atri,
               const __hip_bfloat16* __restrict__ WtT,
               const float* __restrict__ bt1,
               const float* __restrict__ inv,
               float* __restrict__ Hbi, float* __restrict__ Htri,
               int tiles_per)
{
    int bid = blockIdx.x;
    const __hip_bfloat16 *A, *WT;
    const float* b1;
    float* H;
    int Kp, invoff, tile;
    if (bid < tiles_per) { A = Abi;  WT = WbT; b1 = bb1; H = Hbi;  Kp = KP_BI; invoff = 0; tile = bid; }
    else                 { A = Atri; WT = WtT; b1 = bt1; H = Htri; Kp = NTRI;  invoff = 1; tile = bid - tiles_per; }

    const int mt = tile >> 2;          // N has 4 tiles of 64
    const int nt = tile & 3;
    const int m0 = mt * 64, n0 = nt * 64;

    const int wave = threadIdx.x >> 6;
    const int wm = (wave >> 1) * 32, wn = (wave & 1) * 32;
    const int lane = threadIdx.x & 63;
    const int fr   = lane & 15;        // row (A) / col (B) within fragment
    const int kg   = lane >> 4;        // K-group: 8 contiguous elements

    const __hip_bfloat16* A0 = A  + (size_t)(m0 + wm + fr) * Kp + kg * 8;
    const __hip_bfloat16* A1 = A0 + (size_t)16 * Kp;
    const __hip_bfloat16* B0 = WT + (size_t)(n0 + wn + fr) * Kp + kg * 8;
    const __hip_bfloat16* B1 = B0 + (size_t)16 * Kp;

    f32x4 acc00 = {}, acc01 = {}, acc10 = {}, acc11 = {};
    for (int k = 0; k < Kp; k += 32) {
        short8 a0 = *(const short8*)(A0 + k);
        short8 a1 = *(const short8*)(A1 + k);
        short8 b0 = *(const short8*)(B0 + k);
        short8 b1v = *(const short8*)(B1 + k);
        acc00 = __builtin_amdgcn_mfma_f32_16x16x32_bf16(a0, b0,  acc00, 0, 0, 0);
        acc01 = __builtin_amdgcn_mfma_f32_16x16x32_bf16(a0, b1v, acc01, 0, 0, 0);
        acc10 = __builtin_amdgcn_mfma_f32_16x16x32_bf16(a1, b0,  acc10, 0, 0, 0);
        acc11 = __builtin_amdgcn_mfma_f32_16x16x32_bf16(a1, b1v, acc11, 0, 0, 0);
    }

    // D layout: col = lane&15, row = (lane>>4)*4 + reg
    const int drow = kg * 4;
    f32x4 accs[2][2] = { {acc00, acc01}, {acc10, acc11} };
    #pragma unroll
    for (int mf = 0; mf < 2; ++mf) {
        #pragma unroll
        for (int nf = 0; nf < 2; ++nf) {
            int col = n0 + wn + nf * 16 + fr;
            float bias = b1[col];
            #pragma unroll
            for (int r = 0; r < 4; ++r) {
                int row = m0 + wm + mf * 16 + drow + r;
                float iv = inv[row * 2 + invoff];
                H[(size_t)row * NHID + col] = fmaxf(fmaf(accs[mf][nf][r], iv, bias), 0.0f);
            }
        }
    }
}

// ---------------- K3: layer 2 (fp32), both heads ----------------
__global__ __launch_bounds__(256)
void layer2(const float* __restrict__ Hbi, const float* __restrict__ Htri,
            const float* __restrict__ Wb2, const float* __restrict__ bb2,
            const float* __restrict__ Wt2, const float* __restrict__ bt2,
            float* __restrict__ out)
{
    __shared__ float sh[2][8][NHID];   // 16 KB
    const int tid = threadIdx.x;
    const int row0 = blockIdx.x * 8;

    for (int i = tid; i < 8 * NHID; i += 256) {
        int r = i >> 8, j = i & 255;
        sh[0][r][j] = Hbi [(size_t)(row0 + r) * NHID + j];
        sh[1][r][j] = Htri[(size_t)(row0 + r) * NHID + j];
    }
    __syncthreads();

    const int r = tid >> 5, o = tid & 31;
    float a0 = bb2[o], a1 = bt2[o];
    #pragma unroll 4
    for (int j = 0; j < NHID; ++j) {
        a0 = fmaf(sh[0][r][j], Wb2[j * 32 + o], a0);
        a1 = fmaf(sh[1][r][j], Wt2[j * 32 + o], a1);
    }
    size_t ro = (size_t)(row0 + r) * 64;
    out[ro + o]      = a0;
    out[ro + 32 + o] = a1;
}

// ---------------- launcher ----------------
extern "C" void kernel_launch(void* const* d_in, const int* in_sizes, int n_in,
                              void* d_out, int out_size, void* d_ws, size_t ws_size,
                              hipStream_t stream) {
    const int*   src = (const int*)  d_in[0];
    const float* Wb1 = (const float*)d_in[1];
    const float* bb1 = (const float*)d_in[2];
    const float* Wb2 = (const float*)d_in[3];
    const float* bb2 = (const float*)d_in[4];
    const float* Wt1 = (const float*)d_in[5];
    const float* bt1 = (const float*)d_in[6];
    const float* Wt2 = (const float*)d_in[7];
    const float* bt2 = (const float*)d_in[8];
    float* outp = (float*)d_out;

    const int B = in_sizes[0] / TOK_S;           // 4096 rows

    // workspace layout (256B-aligned chunks)
    char* ws = (char*)d_ws;
    __hip_bfloat16* Abi  = (__hip_bfloat16*)(ws);                               // B*1120*2
    __hip_bfloat16* Atri = (__hip_bfloat16*)(ws + (size_t)B * KP_BI * 2);       // B*512*2
    char* ws2 = ws + (size_t)B * KP_BI * 2 + (size_t)B * NTRI * 2;
    __hip_bfloat16* WbT  = (__hip_bfloat16*)(ws2);                              // 256*1120*2
    __hip_bfloat16* WtT  = (__hip_bfloat16*)(ws2 + (size_t)NHID * KP_BI * 2);   // 256*512*2
    char* ws3 = ws2 + (size_t)NHID * KP_BI * 2 + (size_t)NHID * NTRI * 2;
    float* inv  = (float*)(ws3);                                                // B*2*4
    float* Hbi  = (float*)(ws3 + (size_t)B * 2 * 4);                            // B*256*4
    float* Htri = (float*)(ws3 + (size_t)B * 2 * 4 + (size_t)B * NHID * 4);     // B*256*4

    transpose_w<<<(NHID * KP_BI + 255) / 256, 256, 0, stream>>>(Wb1, WbT, NBI, KP_BI);
    transpose_w<<<(NHID * NTRI  + 255) / 256, 256, 0, stream>>>(Wt1, WtT, NTRI, NTRI);

    hist_kernel<<<B, 256, 0, stream>>>(src, Abi, Atri, inv);

    const int tiles_per = (B / 64) * (NHID / 64);      // 256
    gemm_mlp1<<<2 * tiles_per, 256, 0, stream>>>(Abi, WbT, bb1, Atri, WtT, bt1,
                                                 inv, Hbi, Htri, tiles_per);

    layer2<<<B / 8, 256, 0, stream>>>(Hbi, Htri, Wb2, bb2, Wt2, bt2, outp);
}

// Round 3
// 65.236 us; speedup vs baseline: 2.6966x; 1.4530x over previous
//
#include <hip/hip_runtime.h>
#include <hip/hip_bf16.h>

#define TOK_S    4096
#define NBI      1089      // 33*33
#define NBI_P    1092      // LDS pad
#define KP_BI    1120      // A-matrix K padded to multiple of 32
#define NTRI     512
#define NHID     256

typedef __attribute__((ext_vector_type(8))) short short8;   // 8 bf16
typedef __attribute__((ext_vector_type(4))) float f32x4;

// ---------------- K0: transpose + bf16-convert both W1 matrices ----------------
__global__ __launch_bounds__(256)
void transpose_w(const float* __restrict__ Wb1, __hip_bfloat16* __restrict__ WbT,
                 const float* __restrict__ Wt1, __hip_bfloat16* __restrict__ WtT)
{
    int idx = blockIdx.x * 256 + threadIdx.x;
    const int nb = NHID * KP_BI;                 // 286720
    if (idx < nb) {
        int c = idx / KP_BI, k = idx - c * KP_BI;
        float v = (k < NBI) ? Wb1[k * NHID + c] : 0.0f;
        WbT[idx] = __float2bfloat16(v);
    } else {
        idx -= nb;
        if (idx < NHID * NTRI) {
            int c = idx >> 9, k = idx & 511;
            WtT[idx] = __float2bfloat16(Wt1[k * NHID + c]);
        }
    }
}

// ---------------- K1: histograms, tokens in registers ----------------
// Block = 256 threads = 4 waves; waves {0,1} -> row 2*bid, {2,3} -> row 2*bid+1.
// Each wave-pair shares a private histogram; no s_row staging.
__global__ __launch_bounds__(256)
void hist_v3(const int* __restrict__ src,
             __hip_bfloat16* __restrict__ Abi,
             __hip_bfloat16* __restrict__ Atri,
             float* __restrict__ inv)
{
    __shared__ int   s_bi [2][NBI_P];    // 8736 B
    __shared__ int   s_tri[2][NTRI];     // 4096 B
    __shared__ float s_ps [2][2][2];     // partial sums [row][wavepar][bi/tri]

    const int tid  = threadIdx.x;
    const int wave = tid >> 6;
    const int lane = tid & 63;
    const int wrow = wave >> 1;          // row within block
    const int wpar = wave & 1;           // which half of the row
    const size_t row = (size_t)blockIdx.x * 2 + wrow;

    for (int i = tid; i < 2 * NBI_P; i += 256) ((int*)s_bi)[i]  = 0;
    for (int i = tid; i < 2 * NTRI;  i += 256) ((int*)s_tri)[i] = 0;
    __syncthreads();

    int* bi  = s_bi[wrow];
    int* tri = s_tri[wrow];
    const int4* rowp = (const int4*)(src + row * TOK_S);
    const int*  rowt = src + row * TOK_S;

    // each lane: 8 chunks of 4 tokens, chunk idx = wpar*512 + j*64 + lane
    #pragma unroll
    for (int j = 0; j < 8; ++j) {
        const int idx = wpar * 512 + j * 64 + lane;
        int4 c = rowp[idx];
        int e0 = 0, e1 = 0;
        if (idx != 1023) {               // overlap: tokens idx*4+4, +5
            const int2 e = *(const int2*)(rowt + idx * 4 + 4);
            e0 = e.x; e1 = e.y;
        }
        const bool mx = c.x > 0, my = c.y > 0, mz = c.z > 0, mw = c.w > 0;
        const bool m4 = e0 > 0, m5 = e1 > 0;
        const int b0 = c.x * 33 + c.y;
        const int b1 = c.y * 33 + c.z;
        const int b2 = c.z * 33 + c.w;
        const int b3 = c.w * 33 + e0;
        if (mx & my) atomicAdd(&bi[b0], 1);
        if (my & mz) atomicAdd(&bi[b1], 1);
        if (mz & mw) atomicAdd(&bi[b2], 1);
        if (mw & m4) atomicAdd(&bi[b3], 1);
        if (mx & my & mz) atomicAdd(&tri[(b0 * 33 + c.z) & 511], 1);
        if (my & mz & mw) atomicAdd(&tri[(b1 * 33 + c.w) & 511], 1);
        if (mz & mw & m4) atomicAdd(&tri[(b2 * 33 + e0) & 511], 1);
        if (mw & m4 & m5) atomicAdd(&tri[(b3 * 33 + e1) & 511], 1);
    }
    __syncthreads();

    // export: bf16 counts + sums (len = sum of real bins)
    float bsum = 0.0f, tsum = 0.0f;
    __hip_bfloat16* arow = Abi + row * KP_BI;
    for (int i = wpar * 64 + lane; i < KP_BI; i += 128) {
        float f = (i < NBI) ? (float)bi[i] : 0.0f;
        bsum += f;
        arow[i] = __float2bfloat16(f);
    }
    __hip_bfloat16* trow = Atri + row * NTRI;
    for (int i = wpar * 64 + lane; i < NTRI; i += 128) {
        float f = (float)tri[i];
        tsum += f;
        trow[i] = __float2bfloat16(f);
    }
    #pragma unroll
    for (int s = 32; s; s >>= 1) {
        bsum += __shfl_xor(bsum, s, 64);
        tsum += __shfl_xor(tsum, s, 64);
    }
    if (lane == 0) { s_ps[wrow][wpar][0] = bsum; s_ps[wrow][wpar][1] = tsum; }
    __syncthreads();
    if (tid < 2) {
        float bs = s_ps[tid][0][0] + s_ps[tid][1][0];
        float ts = s_ps[tid][0][1] + s_ps[tid][1][1];
        size_t r2 = ((size_t)blockIdx.x * 2 + tid) * 2;
        inv[r2 + 0] = 1.0f / fmaxf(bs, 1.0f);
        inv[r2 + 1] = 1.0f / fmaxf(ts, 1.0f);
    }
}

// ---------------- K2: bf16 MFMA GEMM + relu + /len, constexpr K ----------------
template<int KP>
__global__ __launch_bounds__(256)
void gemm_t(const __hip_bfloat16* __restrict__ A,
            const __hip_bfloat16* __restrict__ WT,
            const float* __restrict__ b1,
            const float* __restrict__ inv, const int invoff,
            float* __restrict__ H)
{
    const int tile = blockIdx.x;
    const int mt = tile >> 2, nt = tile & 3;
    const int m0 = mt * 64, n0 = nt * 64;

    const int wave = threadIdx.x >> 6;
    const int wm = (wave >> 1) * 32, wn = (wave & 1) * 32;
    const int lane = threadIdx.x & 63;
    const int fr   = lane & 15;
    const int kg   = lane >> 4;

    const __hip_bfloat16* A0 = A  + (size_t)(m0 + wm + fr) * KP + kg * 8;
    const __hip_bfloat16* A1 = A0 + (size_t)16 * KP;
    const __hip_bfloat16* B0 = WT + (size_t)(n0 + wn + fr) * KP + kg * 8;
    const __hip_bfloat16* B1 = B0 + (size_t)16 * KP;

    f32x4 acc00 = {}, acc01 = {}, acc10 = {}, acc11 = {};
    #pragma unroll 4
    for (int k = 0; k < KP; k += 32) {
        short8 a0  = *(const short8*)(A0 + k);
        short8 a1  = *(const short8*)(A1 + k);
        short8 b0  = *(const short8*)(B0 + k);
        short8 b1v = *(const short8*)(B1 + k);
        acc00 = __builtin_amdgcn_mfma_f32_16x16x32_bf16(a0, b0,  acc00, 0, 0, 0);
        acc01 = __builtin_amdgcn_mfma_f32_16x16x32_bf16(a0, b1v, acc01, 0, 0, 0);
        acc10 = __builtin_amdgcn_mfma_f32_16x16x32_bf16(a1, b0,  acc10, 0, 0, 0);
        acc11 = __builtin_amdgcn_mfma_f32_16x16x32_bf16(a1, b1v, acc11, 0, 0, 0);
    }

    const int drow = kg * 4;
    f32x4 accs[2][2] = { {acc00, acc01}, {acc10, acc11} };
    #pragma unroll
    for (int mf = 0; mf < 2; ++mf) {
        #pragma unroll
        for (int nf = 0; nf < 2; ++nf) {
            int col = n0 + wn + nf * 16 + fr;
            float bias = b1[col];
            #pragma unroll
            for (int r = 0; r < 4; ++r) {
                int rowi = m0 + wm + mf * 16 + drow + r;
                float iv = inv[rowi * 2 + invoff];
                H[(size_t)rowi * NHID + col] = fmaxf(fmaf(accs[mf][nf][r], iv, bias), 0.0f);
            }
        }
    }
}

// ---------------- K3: layer 2 fp32, no LDS ----------------
__global__ __launch_bounds__(256)
void layer2_v2(const float* __restrict__ Hbi, const float* __restrict__ Htri,
               const float* __restrict__ Wb2, const float* __restrict__ bb2,
               const float* __restrict__ Wt2, const float* __restrict__ bt2,
               float* __restrict__ out)
{
    const int tid = threadIdx.x;
    const int r = blockIdx.x * 8 + (tid >> 5);
    const int o = tid & 31;
    const float* hb = Hbi  + (size_t)r * NHID;
    const float* ht = Htri + (size_t)r * NHID;
    float a0 = bb2[o], a1 = bt2[o];
    #pragma unroll 8
    for (int j = 0; j < NHID; j += 4) {
        float4 h0 = *(const float4*)(hb + j);
        float4 h1 = *(const float4*)(ht + j);
        a0 = fmaf(h0.x, Wb2[(j + 0) * 32 + o], a0);
        a0 = fmaf(h0.y, Wb2[(j + 1) * 32 + o], a0);
        a0 = fmaf(h0.z, Wb2[(j + 2) * 32 + o], a0);
        a0 = fmaf(h0.w, Wb2[(j + 3) * 32 + o], a0);
        a1 = fmaf(h1.x, Wt2[(j + 0) * 32 + o], a1);
        a1 = fmaf(h1.y, Wt2[(j + 1) * 32 + o], a1);
        a1 = fmaf(h1.z, Wt2[(j + 2) * 32 + o], a1);
        a1 = fmaf(h1.w, Wt2[(j + 3) * 32 + o], a1);
    }
    size_t ro = (size_t)r * 64;
    out[ro + o]      = a0;
    out[ro + 32 + o] = a1;
}

// ---------------- launcher ----------------
extern "C" void kernel_launch(void* const* d_in, const int* in_sizes, int n_in,
                              void* d_out, int out_size, void* d_ws, size_t ws_size,
                              hipStream_t stream) {
    const int*   src = (const int*)  d_in[0];
    const float* Wb1 = (const float*)d_in[1];
    const float* bb1 = (const float*)d_in[2];
    const float* Wb2 = (const float*)d_in[3];
    const float* bb2 = (const float*)d_in[4];
    const float* Wt1 = (const float*)d_in[5];
    const float* bt1 = (const float*)d_in[6];
    const float* Wt2 = (const float*)d_in[7];
    const float* bt2 = (const float*)d_in[8];
    float* outp = (float*)d_out;

    const int B = in_sizes[0] / TOK_S;           // 4096 rows

    char* ws = (char*)d_ws;
    __hip_bfloat16* Abi  = (__hip_bfloat16*)(ws);
    __hip_bfloat16* Atri = (__hip_bfloat16*)(ws + (size_t)B * KP_BI * 2);
    char* ws2 = ws + (size_t)B * KP_BI * 2 + (size_t)B * NTRI * 2;
    __hip_bfloat16* WbT  = (__hip_bfloat16*)(ws2);
    __hip_bfloat16* WtT  = (__hip_bfloat16*)(ws2 + (size_t)NHID * KP_BI * 2);
    char* ws3 = ws2 + (size_t)NHID * KP_BI * 2 + (size_t)NHID * NTRI * 2;
    float* inv  = (float*)(ws3);
    float* Hbi  = (float*)(ws3 + (size_t)B * 2 * 4);
    float* Htri = (float*)(ws3 + (size_t)B * 2 * 4 + (size_t)B * NHID * 4);

    const int ttot = NHID * KP_BI + NHID * NTRI;
    transpose_w<<<(ttot + 255) / 256, 256, 0, stream>>>(Wb1, WbT, Wt1, WtT);

    hist_v3<<<B / 2, 256, 0, stream>>>(src, Abi, Atri, inv);

    gemm_t<KP_BI><<<(B / 64) * 4, 256, 0, stream>>>(Abi,  WbT, bb1, inv, 0, Hbi);
    gemm_t<NTRI> <<<(B / 64) * 4, 256, 0, stream>>>(Atri, WtT, bt1, inv, 1, Htri);

    layer2_v2<<<B / 8, 256, 0, stream>>>(Hbi, Htri, Wb2, bb2, Wt2, bt2, outp);
}

// Round 4
// 49.129 us; speedup vs baseline: 3.5807x; 1.3278x over previous
//
#include <hip/hip_runtime.h>
#include <hip/hip_bf16.h>

#define TOK_S    4096
#define NBI      1089      // 33*33
#define NBI_P    1092      // LDS pad
#define KP_BI    1120      // A-matrix K padded to multiple of 32
#define NTRI     512
#define NHID     256
#define NROWS    4096
#define HSTRIDE  (NHID + 4)   // 260: LDS pad for conflict-free reads

#define HIST_BLKS   (NROWS / 2)                       // 2048
#define TRANS_ELEMS (NHID * KP_BI + NHID * NTRI)      // 417792
#define TRANS_BLKS  (TRANS_ELEMS / 1024)              // 408 (exact)

typedef __attribute__((ext_vector_type(8))) short short8;   // 8 bf16
typedef __attribute__((ext_vector_type(4))) float f32x4;

// ============ K1: histograms (2 rows/block) + weight transpose, one grid ============
__global__ __launch_bounds__(256)
void hist_trans(const int* __restrict__ src,
                const float* __restrict__ Wb1, const float* __restrict__ Wt1,
                __hip_bfloat16* __restrict__ Abi,
                __hip_bfloat16* __restrict__ Atri,
                __hip_bfloat16* __restrict__ WbT,
                __hip_bfloat16* __restrict__ WtT,
                float* __restrict__ inv)
{
    __shared__ int   s_bi [2][NBI_P];
    __shared__ int   s_tri[2][NTRI];
    __shared__ float s_ps [2][2][2];

    const int tid = threadIdx.x;

    // ---- transpose blocks (appended after hist blocks) ----
    if (blockIdx.x >= HIST_BLKS) {
        int base = (blockIdx.x - HIST_BLKS) * 1024 + tid;
        const int nb = NHID * KP_BI;
        #pragma unroll
        for (int i = 0; i < 4; ++i) {
            int idx = base + i * 256;
            if (idx < nb) {
                int c = idx / KP_BI, k = idx - c * KP_BI;
                WbT[idx] = __float2bfloat16(k < NBI ? Wb1[k * NHID + c] : 0.0f);
            } else {
                int j = idx - nb;                    // < NHID*NTRI by construction
                int c = j >> 9, k = j & 511;
                WtT[j] = __float2bfloat16(Wt1[k * NHID + c]);
            }
        }
        return;
    }

    // ---- histogram blocks ----
    const int wave = tid >> 6;
    const int lane = tid & 63;
    const int wrow = wave >> 1;          // row within block (0/1)
    const int wpar = wave & 1;           // half of the row
    const size_t row = (size_t)blockIdx.x * 2 + wrow;

    for (int i = tid; i < 2 * NBI_P; i += 256) ((int*)s_bi)[i]  = 0;
    for (int i = tid; i < 2 * NTRI;  i += 256) ((int*)s_tri)[i] = 0;
    __syncthreads();

    int* bi  = s_bi[wrow];
    int* tri = s_tri[wrow];
    const int4* rowp = (const int4*)(src + row * TOK_S);
    const int*  rowt = src + row * TOK_S;

    #pragma unroll
    for (int j = 0; j < 8; ++j) {
        const int idx = wpar * 512 + j * 64 + lane;
        int4 c = rowp[idx];
        int e0 = 0, e1 = 0;
        if (idx != 1023) {
            const int2 e = *(const int2*)(rowt + idx * 4 + 4);
            e0 = e.x; e1 = e.y;
        }
        const bool mx = c.x > 0, my = c.y > 0, mz = c.z > 0, mw = c.w > 0;
        const bool m4 = e0 > 0, m5 = e1 > 0;
        const int b0 = c.x * 33 + c.y;
        const int b1 = c.y * 33 + c.z;
        const int b2 = c.z * 33 + c.w;
        const int b3 = c.w * 33 + e0;
        if (mx & my) atomicAdd(&bi[b0], 1);
        if (my & mz) atomicAdd(&bi[b1], 1);
        if (mz & mw) atomicAdd(&bi[b2], 1);
        if (mw & m4) atomicAdd(&bi[b3], 1);
        if (mx & my & mz) atomicAdd(&tri[(b0 * 33 + c.z) & 511], 1);
        if (my & mz & mw) atomicAdd(&tri[(b1 * 33 + c.w) & 511], 1);
        if (mz & mw & m4) atomicAdd(&tri[(b2 * 33 + e0) & 511], 1);
        if (mw & m4 & m5) atomicAdd(&tri[(b3 * 33 + e1) & 511], 1);
    }
    __syncthreads();

    float bsum = 0.0f, tsum = 0.0f;
    __hip_bfloat16* arow = Abi + row * KP_BI;
    for (int i = wpar * 64 + lane; i < KP_BI; i += 128) {
        float f = (i < NBI) ? (float)bi[i] : 0.0f;
        bsum += f;
        arow[i] = __float2bfloat16(f);
    }
    __hip_bfloat16* trow = Atri + row * NTRI;
    for (int i = wpar * 64 + lane; i < NTRI; i += 128) {
        float f = (float)tri[i];
        tsum += f;
        trow[i] = __float2bfloat16(f);
    }
    #pragma unroll
    for (int s = 32; s; s >>= 1) {
        bsum += __shfl_xor(bsum, s, 64);
        tsum += __shfl_xor(tsum, s, 64);
    }
    if (lane == 0) { s_ps[wrow][wpar][0] = bsum; s_ps[wrow][wpar][1] = tsum; }
    __syncthreads();
    if (tid < 2) {
        float bs = s_ps[tid][0][0] + s_ps[tid][1][0];
        float ts = s_ps[tid][0][1] + s_ps[tid][1][1];
        size_t r2 = ((size_t)blockIdx.x * 2 + tid) * 2;
        inv[r2 + 0] = 1.0f / fmaxf(bs, 1.0f);
        inv[r2 + 1] = 1.0f / fmaxf(ts, 1.0f);
    }
}

// ============ K2: fused layer1 MFMA GEMM (BM=32, N=256) + relu/len + layer2 ============
template<int KP>
__device__ __forceinline__
void head_body(const __hip_bfloat16* __restrict__ A,
               const __hip_bfloat16* __restrict__ WT,
               const float* __restrict__ b1,
               const float* __restrict__ W2,
               const float* __restrict__ b2,
               const float* __restrict__ inv, const int invoff, const int headoff,
               float* __restrict__ out, const int m0,
               float (*sH)[HSTRIDE])
{
    const int wave = threadIdx.x >> 6;       // 8 waves
    const int lane = threadIdx.x & 63;
    const int wn   = wave * 32;              // 32-col strip of N=256
    const int fr   = lane & 15;
    const int kg   = lane >> 4;

    const __hip_bfloat16* A0 = A  + (size_t)(m0 + fr) * KP + kg * 8;
    const __hip_bfloat16* A1 = A0 + (size_t)16 * KP;
    const __hip_bfloat16* B0 = WT + (size_t)(wn + fr) * KP + kg * 8;
    const __hip_bfloat16* B1 = B0 + (size_t)16 * KP;

    f32x4 acc00 = {}, acc01 = {}, acc10 = {}, acc11 = {};
    #pragma unroll 4
    for (int k = 0; k < KP; k += 32) {
        short8 a0  = *(const short8*)(A0 + k);
        short8 a1  = *(const short8*)(A1 + k);
        short8 b0  = *(const short8*)(B0 + k);
        short8 b1v = *(const short8*)(B1 + k);
        acc00 = __builtin_amdgcn_mfma_f32_16x16x32_bf16(a0, b0,  acc00, 0, 0, 0);
        acc01 = __builtin_amdgcn_mfma_f32_16x16x32_bf16(a0, b1v, acc01, 0, 0, 0);
        acc10 = __builtin_amdgcn_mfma_f32_16x16x32_bf16(a1, b0,  acc10, 0, 0, 0);
        acc11 = __builtin_amdgcn_mfma_f32_16x16x32_bf16(a1, b1v, acc11, 0, 0, 0);
    }

    // D layout: col = lane&15 (B side), row = (lane>>4)*4 + reg (A side)
    f32x4 accs[2][2] = { {acc00, acc01}, {acc10, acc11} };
    #pragma unroll
    for (int mf = 0; mf < 2; ++mf) {
        #pragma unroll
        for (int nf = 0; nf < 2; ++nf) {
            const int col = wn + nf * 16 + fr;
            const float bias = b1[col];
            #pragma unroll
            for (int r = 0; r < 4; ++r) {
                const int rl = mf * 16 + kg * 4 + r;
                const float iv = inv[(m0 + rl) * 2 + invoff];
                sH[rl][col] = fmaxf(fmaf(accs[mf][nf][r], iv, bias), 0.0f);
            }
        }
    }
    __syncthreads();

    // ---- layer 2: 32 rows x 32 outs, 2 outs/thread ----
    const int r  = threadIdx.x >> 4;         // 0..31
    const int oo = threadIdx.x & 15;
    const float* hr = sH[r];
    float a0 = b2[oo], a1 = b2[oo + 16];
    #pragma unroll 8
    for (int j = 0; j < NHID; j += 4) {
        float4 h = *(const float4*)(hr + j);
        a0 = fmaf(h.x, W2[(j + 0) * 32 + oo], a0);
        a0 = fmaf(h.y, W2[(j + 1) * 32 + oo], a0);
        a0 = fmaf(h.z, W2[(j + 2) * 32 + oo], a0);
        a0 = fmaf(h.w, W2[(j + 3) * 32 + oo], a0);
        a1 = fmaf(h.x, W2[(j + 0) * 32 + oo + 16], a1);
        a1 = fmaf(h.y, W2[(j + 1) * 32 + oo + 16], a1);
        a1 = fmaf(h.z, W2[(j + 2) * 32 + oo + 16], a1);
        a1 = fmaf(h.w, W2[(j + 3) * 32 + oo + 16], a1);
    }
    const size_t ro = (size_t)(m0 + r) * 64 + headoff;
    out[ro + oo]      = a0;
    out[ro + oo + 16] = a1;
}

__global__ __launch_bounds__(512, 1)
void gemm_fused(const __hip_bfloat16* __restrict__ Abi,
                const __hip_bfloat16* __restrict__ WbT,
                const float* __restrict__ bb1,
                const float* __restrict__ Wb2, const float* __restrict__ bb2,
                const __hip_bfloat16* __restrict__ Atri,
                const __hip_bfloat16* __restrict__ WtT,
                const float* __restrict__ bt1,
                const float* __restrict__ Wt2, const float* __restrict__ bt2,
                const float* __restrict__ inv,
                float* __restrict__ out)
{
    __shared__ float sH[32][HSTRIDE];        // 33.3 KB
    const int bid = blockIdx.x;
    if (bid < NROWS / 32) {
        head_body<KP_BI>(Abi, WbT, bb1, Wb2, bb2, inv, 0, 0,  out, bid * 32, sH);
    } else {
        head_body<NTRI>(Atri, WtT, bt1, Wt2, bt2, inv, 1, 32, out, (bid - NROWS / 32) * 32, sH);
    }
}

// ============ launcher ============
extern "C" void kernel_launch(void* const* d_in, const int* in_sizes, int n_in,
                              void* d_out, int out_size, void* d_ws, size_t ws_size,
                              hipStream_t stream) {
    const int*   src = (const int*)  d_in[0];
    const float* Wb1 = (const float*)d_in[1];
    const float* bb1 = (const float*)d_in[2];
    const float* Wb2 = (const float*)d_in[3];
    const float* bb2 = (const float*)d_in[4];
    const float* Wt1 = (const float*)d_in[5];
    const float* bt1 = (const float*)d_in[6];
    const float* Wt2 = (const float*)d_in[7];
    const float* bt2 = (const float*)d_in[8];
    float* outp = (float*)d_out;

    const int B = in_sizes[0] / TOK_S;           // 4096 rows

    char* ws = (char*)d_ws;
    __hip_bfloat16* Abi  = (__hip_bfloat16*)(ws);
    __hip_bfloat16* Atri = (__hip_bfloat16*)(ws + (size_t)B * KP_BI * 2);
    char* ws2 = ws + (size_t)B * KP_BI * 2 + (size_t)B * NTRI * 2;
    __hip_bfloat16* WbT  = (__hip_bfloat16*)(ws2);
    __hip_bfloat16* WtT  = (__hip_bfloat16*)(ws2 + (size_t)NHID * KP_BI * 2);
    float* inv = (float*)(ws2 + (size_t)NHID * KP_BI * 2 + (size_t)NHID * NTRI * 2);

    hist_trans<<<HIST_BLKS + TRANS_BLKS, 256, 0, stream>>>(
        src, Wb1, Wt1, Abi, Atri, WbT, WtT, inv);

    gemm_fused<<<2 * (B / 32), 512, 0, stream>>>(
        Abi, WbT, bb1, Wb2, bb2, Atri, WtT, bt1, Wt2, bt2, inv, outp);
}